// Round 17
// baseline (201.801 us; speedup 1.0000x reference)
//
#include <hip/hip_runtime.h>
#include <stdint.h>

#define N_OUT_  4096
#define N_IN_   4096
#define BATCH_  4096
#define NNZ_    1600000

typedef unsigned short ushort_t;
typedef float  f32x4  __attribute__((ext_vector_type(4)));
typedef short  short8 __attribute__((ext_vector_type(8)));
typedef __bf16 bf16x8 __attribute__((ext_vector_type(8)));

// RNE f32 -> bf16
__device__ inline ushort_t f32_to_bf16(float f) {
  uint32_t u = __float_as_uint(f);
  uint32_t r = u + 0x7FFFu + ((u >> 16) & 1u);
  return (ushort_t)(r >> 16);
}
__device__ inline float bf16_to_f32(ushort_t h) {
  return __uint_as_float(((uint32_t)h) << 16);
}

// async global->LDS, 16B/lane; LDS dest wave-uniform base + lane*16 (linear)
__device__ inline void gload_lds16(const void* g, void* l) {
  __builtin_amdgcn_global_load_lds(
      (const __attribute__((address_space(1))) void*)g,
      (__attribute__((address_space(3))) void*)l,
      16, 0, 0);
}

__device__ inline f32x4 mfma_bf16(short8 a, short8 b, f32x4 c) {
  return __builtin_amdgcn_mfma_f32_16x16x32_bf16(
      __builtin_bit_cast(bf16x8, a), __builtin_bit_cast(bf16x8, b), c, 0, 0, 0);
}

#define BARRIER() asm volatile("s_barrier" ::: "memory")
__device__ __forceinline__ void waitvm0() {
  asm volatile("s_waitcnt vmcnt(0)" ::: "memory");
}

// ------- fused scatter (2 indep CAS chains/thread) + 64x64 transpose --------
// (FROZEN since r12: scatter is at the device atomic-throughput wall)
#define SC_BLOCKS2 3125       // 3125*256*2 == NNZ_
#define TR_TOTAL 4096         // (4096/64)^2
#define FUSED_BLOCKS 7294     // 1042 periods of 7 (3 scatter + 4 transpose)
#define HALF_NNZ 800000

__device__ inline void cas_add_bf16(uint32_t* __restrict__ W32, int i,
                                    const float* __restrict__ vals,
                                    const int* __restrict__ rows,
                                    const int* __restrict__ cols) {
  const size_t idx =
      (size_t)__builtin_nontemporal_load(rows + i) * N_IN_ +
      __builtin_nontemporal_load(cols + i);
  const float v = __builtin_nontemporal_load(vals + i);
  uint32_t* p = &W32[idx >> 1];
  const bool hi = (idx & 1) != 0;
  uint32_t cur = 0u;   // optimistic: W freshly zeroed
  while (true) {
    ushort_t h = hi ? (ushort_t)(cur >> 16) : (ushort_t)(cur & 0xFFFFu);
    ushort_t nh = f32_to_bf16(bf16_to_f32(h) + v);
    uint32_t nw = hi ? ((cur & 0x0000FFFFu) | ((uint32_t)nh << 16))
                     : ((cur & 0xFFFF0000u) | (uint32_t)nh);
    uint32_t got = atomicCAS(p, cur, nw);
    if (got == cur) break;
    cur = got;
  }
}

__global__ __launch_bounds__(256) void scatter_transpose(
    const float* __restrict__ vals, const int* __restrict__ rows,
    const int* __restrict__ cols, uint32_t* __restrict__ W32,
    const float* __restrict__ in, ushort_t* __restrict__ out) {
  const int b = blockIdx.x;
  const int m = b % 7;
  if (m < 3) {
    const int sb = (b / 7) * 3 + m;
    if (sb >= SC_BLOCKS2) return;
    const int i = sb * 256 + threadIdx.x;           // < 800000
    cas_add_bf16(W32, i, vals, rows, cols);
    cas_add_bf16(W32, i + HALF_NNZ, vals, rows, cols);
  } else {
    const int tb = (b / 7) * 4 + (m - 3);
    if (tb >= TR_TOTAL) return;
    // 64x64 tile transpose: in f32[K][BATCH] -> out bf16[BATCH][K]
    __shared__ float tile[64][65];
    const int bx = (tb & 63) * 64;           // batch base
    const int by = (tb >> 6) * 64;           // k base
    const int t = threadIdx.x;
    const int lr = t >> 4;
    const int lc = (t & 15) * 4;
#pragma unroll
    for (int p = 0; p < 4; ++p) {
      const int i = lr + 16 * p;
      *(float4*)&tile[i][lc] =
          *(const float4*)&in[(size_t)(by + i) * BATCH_ + bx + lc];
    }
    __syncthreads();
    const int s = t & 7;
    const int j0 = t >> 3;
#pragma unroll
    for (int q = 0; q < 2; ++q) {
      const int j = j0 + 32 * q;
      uint32_t w0, w1, w2, w3;
      w0 = (uint32_t)f32_to_bf16(tile[8 * s + 0][j]) |
           ((uint32_t)f32_to_bf16(tile[8 * s + 1][j]) << 16);
      w1 = (uint32_t)f32_to_bf16(tile[8 * s + 2][j]) |
           ((uint32_t)f32_to_bf16(tile[8 * s + 3][j]) << 16);
      w2 = (uint32_t)f32_to_bf16(tile[8 * s + 4][j]) |
           ((uint32_t)f32_to_bf16(tile[8 * s + 5][j]) << 16);
      w3 = (uint32_t)f32_to_bf16(tile[8 * s + 6][j]) |
           ((uint32_t)f32_to_bf16(tile[8 * s + 7][j]) << 16);
      uint4 w = {w0, w1, w2, w3};
      *(uint4*)&out[(size_t)(bx + j) * N_IN_ + by + 8 * s] = w;
    }
  }
}

// ------ 256x256 GEMM, BK=64 ring-2, ONE barrier per K-tile ------------------
// C[m][n] = relu(sum_k A[m][k]*Bt[n][k] + bias[m])
// TILE(t): {read ku0 frags (12) | stage A(t+1) x4 | read ku1 frags (12) |
//           stage B(t+1) x4 | 32 MFMA ku0 | 32 MFMA ku1 | vmcnt(0) | BAR}
// Barriers per 64 K-elems: 1 (r5 had 4). vmcnt(0) is ~free: last stage
// issues >=1 full MFMA cluster (~1200cyc) before the wait >> L2 latency.
// Ring-2 audit: stage(t+1) -> buf !(t&1); its old readers (tile t-1) done
// before end-of-(t-1) BAR; buf t+1 visible after end-of-t vmcnt(0)+BAR.
// Swizzle (row stride 128B): off ^= ((off>>7)&7)<<4 — involution (bits 7-9
// disjoint from 4-6); XOR term = (fr&7)<<4 lane-constant => base+imm folds;
// enumerated 8 lanes/bank-quad uniform => conflict-free. Stage source
// pre-swizzled (rule #21): lane l fetches k-slot (l&7)^(l>>3) of row l>>3.
#define BM 256
#define BN 256
#define BK 64
#define KTILES 64
#define BUF_BYTES 65536       // A 32K + B 32K
#define B_OFF_L 32768

__global__ __launch_bounds__(512, 2) void gemm_bias_relu(
    const ushort_t* __restrict__ A,    // bf16 [N_OUT][N_IN]
    const ushort_t* __restrict__ Bt,   // bf16 [BATCH][N_IN]
    const float* __restrict__ bias,    // [N_OUT]
    float* __restrict__ C) {           // f32 [N_OUT][BATCH]
  __shared__ __align__(16) char smem[2 * BUF_BYTES];  // 128 KiB

  const int tid  = threadIdx.x;
  const int wid  = tid >> 6;
  const int lane = tid & 63;

  // T1: XCD swizzle (nwg=256, 8 XCDs, bijective)
  const int bid = blockIdx.x;
  const int swz = (bid & 7) * 32 + (bid >> 3);
  const int brow = (swz >> 4) * BM;
  const int bcol = (swz & 15) * BN;

  const int wr = wid >> 2;        // 0..1 -> rows wr*128..+128
  const int wc = wid & 3;         // 0..3 -> cols wc*64..+64
  const int fr = lane & 15;
  const int k0slot = lane >> 4;   // 0..3

  // frag LDS byte offsets: off = row*128 + ku*64 + k0slot*16, 3-bit XOR swz
  int aoff[16], boff[8];          // [mi*2+ku], [ni*2+ku]
#pragma unroll
  for (int mi = 0; mi < 8; ++mi)
#pragma unroll
    for (int ku = 0; ku < 2; ++ku) {
      int off = (wr * 128 + mi * 16 + fr) * 128 + ku * 64 + k0slot * 16;
      aoff[mi * 2 + ku] = off ^ (((off >> 7) & 7) << 4);
    }
#pragma unroll
  for (int ni = 0; ni < 4; ++ni)
#pragma unroll
    for (int ku = 0; ku < 2; ++ku) {
      int off = (wc * 64 + ni * 16 + fr) * 128 + ku * 64 + k0slot * 16;
      boff[ni * 2 + ku] = off ^ (((off >> 7) & 7) << 4);
    }

  // staging: waves 0-3 -> A (rows sw*64..+64), waves 4-7 -> B; 8 gloads each.
  // chunk c = sw*8+j (1KB = 8 rows x 128B); lane l: row = c*8 + (l>>3),
  // k-slot fetched = (l&7)^(l>>3)  (pre-swizzled source, linear LDS dest)
  const bool isB = wid >= 4;
  const int sw = isB ? wid - 4 : wid;
  const int l3 = lane >> 3;                 // 0..7
  const int kslot = (lane & 7) ^ l3;        // 0..7
  const ushort_t* gsrc = isB ? Bt : A;
  const size_t laneRowBase =
      (size_t)((isB ? bcol : brow) + sw * 64 + l3) * N_IN_ + kslot * 8;
  const int ldsOpBase = isB ? B_OFF_L : 0;

#define STAGE(j, t)                                                           \
  gload_lds16(gsrc + laneRowBase + (size_t)(j) * 8 * N_IN_ +                  \
                  (size_t)(t) * BK,                                           \
              smem + ((t) & 1) * BUF_BYTES + ldsOpBase + (sw * 8 + (j)) * 1024)

  f32x4 acc[8][4] = {};
  short8 a0[8], b0[4], a1[8], b1[4];

  // prologue: stage tile 0 fully; drain; barrier
#pragma unroll
  for (int j = 0; j < 8; ++j) STAGE(j, 0);
  waitvm0();
  BARRIER();

#define TILE(t, S_ON)                                                         \
  do {                                                                        \
    const char* buf = &smem[((t) & 1) * BUF_BYTES];                           \
    _Pragma("unroll") for (int ni = 0; ni < 4; ++ni)                          \
        b0[ni] = *(const short8*)(buf + B_OFF_L + boff[ni * 2]);              \
    _Pragma("unroll") for (int mi = 0; mi < 8; ++mi)                          \
        a0[mi] = *(const short8*)(buf + aoff[mi * 2]);                        \
    if (S_ON) { STAGE(0, (t) + 1); STAGE(1, (t) + 1);                         \
                STAGE(2, (t) + 1); STAGE(3, (t) + 1); }                       \
    _Pragma("unroll") for (int ni = 0; ni < 4; ++ni)                          \
        b1[ni] = *(const short8*)(buf + B_OFF_L + boff[ni * 2 + 1]);          \
    _Pragma("unroll") for (int mi = 0; mi < 8; ++mi)                          \
        a1[mi] = *(const short8*)(buf + aoff[mi * 2 + 1]);                    \
    if (S_ON) { STAGE(4, (t) + 1); STAGE(5, (t) + 1);                         \
                STAGE(6, (t) + 1); STAGE(7, (t) + 1); }                       \
    __builtin_amdgcn_s_setprio(1);                                            \
    _Pragma("unroll") for (int mi = 0; mi < 8; ++mi)                          \
        _Pragma("unroll") for (int ni = 0; ni < 4; ++ni)                      \
            acc[mi][ni] = mfma_bf16(a0[mi], b0[ni], acc[mi][ni]);             \
    __builtin_amdgcn_s_setprio(0);                                            \
    __builtin_amdgcn_s_setprio(1);                                            \
    _Pragma("unroll") for (int mi = 0; mi < 8; ++mi)                          \
        _Pragma("unroll") for (int ni = 0; ni < 4; ++ni)                      \
            acc[mi][ni] = mfma_bf16(a1[mi], b1[ni], acc[mi][ni]);             \
    __builtin_amdgcn_s_setprio(0);                                            \
    waitvm0();                                                                \
    BARRIER();                                                                \
  } while (0)

  // main: tiles 0..62 stage t+1; tile 63 no stage
  for (int t = 0; t < KTILES - 1; ++t) TILE(t, 1);
  TILE(KTILES - 1, 0);

  // epilogue: C/D map col = lane&15, row = (lane>>4)*4 + reg
  const int r0 = brow + wr * 128 + k0slot * 4;
  const int c0 = bcol + wc * 64 + fr;
#pragma unroll
  for (int mi = 0; mi < 8; ++mi) {
#pragma unroll
    for (int r = 0; r < 4; ++r) {
      const int row = r0 + mi * 16 + r;
      const float b = bias[row];
#pragma unroll
      for (int ni = 0; ni < 4; ++ni) {
        float v = acc[mi][ni][r] + b;
        C[(size_t)row * BATCH_ + c0 + ni * 16] = v > 0.f ? v : 0.f;
      }
    }
  }
#undef TILE
#undef STAGE
}

extern "C" void kernel_launch(void* const* d_in, const int* in_sizes, int n_in,
                              void* d_out, int out_size, void* d_ws, size_t ws_size,
                              hipStream_t stream) {
  const float* inputs = (const float*)d_in[0];
  const float* values = (const float*)d_in[1];
  const float* biases = (const float*)d_in[2];
  const int*   rows   = (const int*)d_in[3];
  const int*   cols   = (const int*)d_in[4];
  float* out = (float*)d_out;

  // layout: [0,32M) bf16 W ; [32M,64M) bf16 in^T
  const size_t W_BF16_BYTES = (size_t)N_OUT_ * N_IN_ * 2;  // 32 MiB
  if (ws_size < 2 * W_BF16_BYTES) return;
  char* ws = (char*)d_ws;
  ushort_t* Wb = (ushort_t*)ws;
  ushort_t* Bt = (ushort_t*)(ws + W_BF16_BYTES);

  hipMemsetAsync(Wb, 0, W_BF16_BYTES, stream);
  scatter_transpose<<<FUSED_BLOCKS, 256, 0, stream>>>(
      values, rows, cols, (uint32_t*)Wb, inputs, Bt);
  gemm_bias_relu<<<dim3(256), 512, 0, stream>>>(Wb, Bt, biases, out);
}